// Round 9
// baseline (55.343 us; speedup 1.0000x reference)
//
#include <hip/hip_runtime.h>

#define NFEAT   100000
#define NBATCH  256
#define DIM     128
#define MARGIN_F 0.5f
#define GRID    625                       // blocks; 625*10*16 = 100000 exactly
#define IPB     10                        // chunks per block
#define CROWS   16                        // feature rows per staged chunk
#define ROWS_PB (IPB * CROWS)             // 160 feature rows per block
#define CBYTES  (CROWS * DIM * 4)         // 8 KiB per chunk
#define FLT_BIG 3.402823466e+38f

typedef __bf16 bf8_t  __attribute__((ext_vector_type(8)));
typedef short  sh8_t  __attribute__((ext_vector_type(8)));
typedef float  f32x4  __attribute__((ext_vector_type(4)));

// f32 -> bf16 native cast: compiler emits v_cvt_pk_bf16_f32 pairs (RTNE).
__device__ __forceinline__ bf8_t pack8(float4 v0, float4 v1) {
  bf8_t r;
  r[0] = (__bf16)v0.x; r[1] = (__bf16)v0.y; r[2] = (__bf16)v0.z; r[3] = (__bf16)v0.w;
  r[4] = (__bf16)v1.x; r[5] = (__bf16)v1.y; r[6] = (__bf16)v1.z; r[7] = (__bf16)v1.w;
  return r;
}

// MFMA dispatch: works whether the builtin takes bf16-vectors or short-vectors
template <typename VA, typename VC>
__device__ __forceinline__ auto mfma_sel(VA a, VA b, VC c, int)
    -> decltype(__builtin_amdgcn_mfma_f32_16x16x32_bf16(a, b, c, 0, 0, 0)) {
  return __builtin_amdgcn_mfma_f32_16x16x32_bf16(a, b, c, 0, 0, 0);
}
template <typename VA, typename VC>
__device__ __forceinline__ VC mfma_sel(VA a, VA b, VC c, long) {
  return __builtin_amdgcn_mfma_f32_16x16x32_bf16(
      __builtin_bit_cast(sh8_t, a), __builtin_bit_cast(sh8_t, b), c, 0, 0, 0);
}
__device__ __forceinline__ f32x4 mfma_bf16(bf8_t a, bf8_t b, f32x4 c) {
  return mfma_sel(a, b, c, 0);
}

#define CFENCE()  asm volatile("" ::: "memory")

// Kernel 1: fused GEMM + masked min/max partial reduction.
// R9 change: REG-STAGED staging (T14, HipKittens-style) instead of
// global_load_lds DMA. Rationale: ds_read of DMA-written LDS forces the
// compiler to insert a conservative s_waitcnt vmcnt(0) before the reads
// (it can't prove which outstanding DMA wrote the buffer), draining the
// prefetch queue EVERY iteration -> all prior pipelines ran at full memory
// latency per iteration (~5400 cyc observed vs ~500 issue work). With reg
// destinations the compiler's vmcnt insertion is per-register and precise:
//   iter c: issue load(c+3)->regs | compute c from LDS | ds_write(c+1)
//           [counted vmcnt, auto] | lgkmcnt(0) | barrier
// Load->ds_write gap = 2 iterations of latency cover. LDS: 2 x 8KB buffers.
// Persistent blocks: 625 x 160 contiguous rows = 10 chunks, no tail.
// 8 waves; wave w owns batch rows [32w,32w+32) (2 M-tiles).
// Swizzle now applied on the ds_write ADDRESS (global reads are linear);
// reads undo it (byte ^= (row&7)<<4), bank-uniform ds_read_b128.
// MFMA 16x16x32 layouts (guide §3, m89/m91-verified):
//   A: lane l holds A[m0 + (l&15)][k0 + (l>>4)*8 + e]
//   B: lane l holds B[k0 + (l>>4)*8 + e][j0 + (l&15)]   (= features[j][k])
//   D: lane l reg r = sim[m0 + (l>>4)*4 + r][j0 + (l&15)]
__global__ __launch_bounds__(512, 2) void triplet_partial(
    const float* __restrict__ inputs, const float* __restrict__ features,
    const int* __restrict__ targets, const int* __restrict__ flabels,
    const int* __restrict__ idx,
    float* __restrict__ ppos, float* __restrict__ pneg,
    float* __restrict__ out)
{
  __shared__ char sbuf[2][CBYTES];      // 16 KiB double buffer
  __shared__ int  slab[ROWS_PB];        // labels for this block's 160 rows

  const int tid  = threadIdx.x;
  const int lane = tid & 63;
  const int wv   = tid >> 6;      // 0..7
  const int l15  = lane & 15;
  const int lg   = lane >> 4;     // 0..3
  const int m0   = wv * 32;
  const int blk  = blockIdx.x;
  const int rowbase = blk * ROWS_PB;   // first feature row of this block

  if (blk == 0 && tid == 0) out[0] = 0.0f;   // K2 accumulates atomically

  // linear global source: thread tid reads bytes [tid*16, tid*16+16) of chunk c
  const char* gbase = (const char*)features + (size_t)rowbase * 512 + tid * 16;
  // swizzled LDS write dest (same XOR the read side undoes)
  const int p    = tid * 16;
  const int prow = p >> 9;                         // 0..15
  const int pdst = p ^ ((prow & 7) << 4);          // row part untouched (bits>=9)

  // ---- prologue: issue the 3 stage loads FIRST (oldest in vmcnt queue),
  // then A/meta/label loads; convert A; write chunk0; barrier.
  float4 rst[3];
  rst[0] = *reinterpret_cast<const float4*>(gbase + 0 * CBYTES);
  rst[1] = *reinterpret_cast<const float4*>(gbase + 1 * CBYTES);
  rst[2] = *reinterpret_cast<const float4*>(gbase + 2 * CBYTES);

  bf8_t afrag[2][4];
#pragma unroll
  for (int mt = 0; mt < 2; ++mt) {
    const float* ap = inputs + (m0 + mt * 16 + l15) * DIM;
    float4 v0[4], v1[4];
#pragma unroll
    for (int ks = 0; ks < 4; ++ks) {
      const int k = ks * 32 + lg * 8;
      v0[ks] = *reinterpret_cast<const float4*>(ap + k);
      v1[ks] = *reinterpret_cast<const float4*>(ap + k + 4);
    }
#pragma unroll
    for (int ks = 0; ks < 4; ++ks)
      afrag[mt][ks] = pack8(v0[ks], v1[ks]);
  }

  // packed row metadata: meta = (self_gallery_row << 10) | target_label
  int meta[2][4];
#pragma unroll
  for (int mt = 0; mt < 2; ++mt)
#pragma unroll
    for (int rr = 0; rr < 4; ++rr) {
      const int row = m0 + mt * 16 + lg * 4 + rr;
      meta[mt][rr] = (idx[row] << 10) | targets[row];
    }

  int labv = 0;
  if (tid < ROWS_PB) labv = flabels[rowbase + tid];

  // chunk 0 -> LDS (compiler inserts the precise counted vmcnt for rst[0])
  *reinterpret_cast<float4*>(&sbuf[0][pdst]) = rst[0];
  if (tid < ROWS_PB) slab[tid] = labv;

  float minpos[2][4], maxneg[2][4];
#pragma unroll
  for (int mt = 0; mt < 2; ++mt)
#pragma unroll
    for (int rr = 0; rr < 4; ++rr) { minpos[mt][rr] = FLT_BIG; maxneg[mt][rr] = -FLT_BIG; }

  asm volatile("s_waitcnt lgkmcnt(0)" ::: "memory");  // buf0 + slab visible
  __builtin_amdgcn_s_barrier();
  CFENCE();

  // ---- main loop (fully unrolled; all rst indices compile-time static)
#pragma unroll
  for (int c = 0; c < IPB; ++c) {
    // 1) issue stage load for chunk c+3 (lands ~2 iterations from its use)
    if (c + 3 < IPB)
      rst[(c + 3) % 3] = *reinterpret_cast<const float4*>(gbase + (size_t)(c + 3) * CBYTES);

    // 2) compute chunk c from sbuf[c&1]
    const int jcol = c * CROWS + l15;     // 0..159
    const int j    = rowbase + jcol;
    const int labj = slab[jcol];

    bf8_t bfrag[4];
    const char* rbase = &sbuf[c & 1][l15 * 512];
    const int   swz   = (l15 & 7) << 4;
#pragma unroll
    for (int ks = 0; ks < 4; ++ks) {
      const int b0 = ks * 128 + lg * 32;
      float4 v0 = *reinterpret_cast<const float4*>(rbase + ((b0)      ^ swz));
      float4 v1 = *reinterpret_cast<const float4*>(rbase + ((b0 + 16) ^ swz));
      bfrag[ks] = pack8(v0, v1);
    }

#pragma unroll
    for (int mt = 0; mt < 2; ++mt) {
      f32x4 acc = {0.f, 0.f, 0.f, 0.f};
#pragma unroll
      for (int ks = 0; ks < 4; ++ks)
        acc = mfma_bf16(afrag[mt][ks], bfrag[ks], acc);
#pragma unroll
      for (int rr = 0; rr < 4; ++rr) {
        const float s    = acc[rr];
        const int   m    = meta[mt][rr];
        const bool same  = (labj == (m & 1023));
        const bool self  = (j == (m >> 10));
        minpos[mt][rr] = fminf(minpos[mt][rr], (same && !self) ? s : FLT_BIG);
        maxneg[mt][rr] = fmaxf(maxneg[mt][rr], same ? -FLT_BIG : s);
      }
    }

    // 3) write chunk c+1 into the buffer we just finished reading last iter.
    //    Compiler emits a COUNTED vmcnt wait for exactly rst[(c+1)%3]'s load
    //    (issued 2 iterations ago) -- prefetches for c+2/c+3 stay in flight.
    if (c + 1 < IPB)
      *reinterpret_cast<float4*>(&sbuf[(c + 1) & 1][pdst]) = rst[(c + 1) % 3];

    // 4) my LDS write visible, then block-wide rendezvous
    asm volatile("s_waitcnt lgkmcnt(0)" ::: "memory");
    __builtin_amdgcn_s_barrier();
    CFENCE();
  }

  // Reduce over the 16 cols held across each 16-lane group; coalesced write
#pragma unroll
  for (int mt = 0; mt < 2; ++mt)
#pragma unroll
    for (int rr = 0; rr < 4; ++rr) {
      float mp = minpos[mt][rr], mn = maxneg[mt][rr];
#pragma unroll
      for (int m = 1; m < 16; m <<= 1) {
        mp = fminf(mp, __shfl_xor(mp, m, 64));
        mn = fmaxf(mn, __shfl_xor(mn, m, 64));
      }
      if (l15 == 0) {
        const int row = m0 + mt * 16 + lg * 4 + rr;
        ppos[blk * NBATCH + row] = mp;   // [blk][row]: contiguous per block
        pneg[blk * NBATCH + row] = mn;
      }
    }
}

// Kernel 2: one block per batch row; fold GRID partials (L2-resident), hinge,
// atomic mean-accumulate into out[0] (zeroed by K1 block 0).
__global__ __launch_bounds__(256) void triplet_reduce(
    const float* __restrict__ ppos, const float* __restrict__ pneg,
    float* __restrict__ out)
{
  const int r = blockIdx.x;
  const int t = threadIdx.x;
  float mp = FLT_BIG, mn = -FLT_BIG;
  for (int b = t; b < GRID; b += 256) {
    mp = fminf(mp, ppos[b * NBATCH + r]);
    mn = fmaxf(mn, pneg[b * NBATCH + r]);
  }
#pragma unroll
  for (int m = 1; m < 64; m <<= 1) {
    mp = fminf(mp, __shfl_xor(mp, m, 64));
    mn = fmaxf(mn, __shfl_xor(mn, m, 64));
  }
  __shared__ float smp[4], smn[4];
  if ((t & 63) == 0) { smp[t >> 6] = mp; smn[t >> 6] = mn; }
  __syncthreads();
  if (t == 0) {
    mp = fminf(fminf(smp[0], smp[1]), fminf(smp[2], smp[3]));
    mn = fmaxf(fmaxf(smn[0], smn[1]), fmaxf(smn[2], smn[3]));
    float loss = mn - mp + MARGIN_F;
    loss = loss > 0.f ? loss : 0.f;
    atomicAdd(out, loss * (1.0f / NBATCH));
  }
}

extern "C" void kernel_launch(void* const* d_in, const int* in_sizes, int n_in,
                              void* d_out, int out_size, void* d_ws, size_t ws_size,
                              hipStream_t stream) {
  const float* inputs   = (const float*)d_in[0];
  const float* features = (const float*)d_in[1];
  const int*   targets  = (const int*)d_in[2];
  const int*   flabels  = (const int*)d_in[3];
  const int*   idx      = (const int*)d_in[4];
  float* out  = (float*)d_out;
  float* ppos = (float*)d_ws;                 // [GRID][256]
  float* pneg = ppos + (size_t)GRID * NBATCH; // [GRID][256]  (~1.28 MB total)

  triplet_partial<<<GRID, 512, 0, stream>>>(inputs, features, targets, flabels, idx, ppos, pneg, out);
  triplet_reduce<<<NBATCH, 256, 0, stream>>>(ppos, pneg, out);
}